// Round 2
// baseline (267.433 us; speedup 1.0000x reference)
//
#include <hip/hip_runtime.h>
#include <hip/hip_bf16.h>
#include <cstdint>
#include <cstddef>

typedef __hip_bfloat16 bf16;
using short8 = __attribute__((ext_vector_type(8))) short;
using f32x4  = __attribute__((ext_vector_type(4))) float;

static constexpr int   kNC    = 1026;   // n_fft + 2
static constexpr int   kKS    = 1088;   // padded S_ri cols (17*64)
static constexpr float kTwoPi = 6.283185307179586f;

#define GLDS(g, l) __builtin_amdgcn_global_load_lds(                       \
    (const __attribute__((address_space(1))) uint32_t*)(g),                \
    (__attribute__((address_space(3))) uint32_t*)(l), 16, 0, 0)

// ---------------------------------------------------------------- prep: x -> bf16
// 16,777,216 elements, 8 per thread, 256 threads/block -> 8192 blocks.
__global__ void cvt_x_k(const float* __restrict__ x, bf16* __restrict__ xb) {
    size_t i = ((size_t)blockIdx.x * 256 + threadIdx.x) * 8;
    float4 a = *(const float4*)(x + i);
    float4 c = *(const float4*)(x + i + 4);
    union { bf16 h[8]; uint4 u; } o;
    o.h[0] = __float2bfloat16(a.x); o.h[1] = __float2bfloat16(a.y);
    o.h[2] = __float2bfloat16(a.z); o.h[3] = __float2bfloat16(a.w);
    o.h[4] = __float2bfloat16(c.x); o.h[5] = __float2bfloat16(c.y);
    o.h[6] = __float2bfloat16(c.z); o.h[7] = __float2bfloat16(c.w);
    *(uint4*)(xb + i) = o.u;
}

// ------------------------------------------- prep: W -> Wr [1152][512] interleaved
// col j of Wr: j=2k -> W col k (mag), j=2k+1 -> W col 513+k (phase), k=0..511;
// j=1024 -> W col 512 (mag Nyquist), j=1025 -> W col 1025 (phase Nyquist); else 0.
__global__ void prep_w_k(const float* __restrict__ W, const float* __restrict__ b,
                         bf16* __restrict__ Wr, float* __restrict__ br) {
    int j = blockIdx.x;
    int col = -1;
    if (j < 1024)      col = (j & 1) ? 513 + (j >> 1) : (j >> 1);
    else if (j == 1024) col = 512;
    else if (j == 1025) col = 1025;
    for (int k = threadIdx.x; k < 512; k += 256) {
        float v = (col >= 0) ? W[(size_t)k * 1026 + col] : 0.0f;
        Wr[(size_t)j * 512 + k] = __float2bfloat16(v);
    }
    if (threadIdx.x == 0) br[j] = (col >= 0) ? b[col] : 0.0f;
}

// --------------------- prep: windowed irfft matrix Mw [1024 rows n][1088 cols kk]
// kk=2k: alpha_k*cos(2*pi*k*n/1024)*w[n]/1024 ; kk=2k+1: -alpha_k*sin(...)*w[n]/1024
__global__ void prep_m_k(bf16* __restrict__ Mw, float* __restrict__ w2) {
    int nrow = blockIdx.x;
    float wn = 0.5f - 0.5f * cosf(kTwoPi * (float)nrow / 1023.0f);  // numpy hanning
    for (int kk = threadIdx.x; kk < 1088; kk += 256) {
        float v = 0.0f;
        if (kk < 1026) {
            int k = kk >> 1;
            int mm = (k * nrow) & 1023;
            float ang = kTwoPi * (float)mm * (1.0f / 1024.0f);
            float alpha = (k == 0 || k == 512) ? 1.0f : 2.0f;
            float tw = (kk & 1) ? -sinf(ang) : cosf(ang);
            v = alpha * (1.0f / 1024.0f) * wn * tw;
        }
        Mw[(size_t)nrow * 1088 + kk] = __float2bfloat16(v);
    }
    if (threadIdx.x == 0) w2[nrow] = wn * wn;
}

// -------------------------------------------------------------------- bf16 GEMM
// C(M x N) = A(M x K, row-major) * B^T stored [n][k]; 128x128 tile, 4 waves 2x2,
// each wave 64x64 = 4x4 fragments of 16x16x32 MFMA. EPI=1: Vocos S_ri epilogue.
template<int K, int LDO, int EPI>
__global__ __launch_bounds__(256)
void gemm_k(const bf16* __restrict__ A, const bf16* __restrict__ B,
            const float* __restrict__ bias, bf16* __restrict__ O)
{
    __shared__ __align__(16) bf16 lsA[128 * 64];
    __shared__ __align__(16) bf16 lsB[128 * 64];
    const int tid  = threadIdx.x;
    const int w    = tid >> 6;
    const int lane = tid & 63;
    const int wr = w >> 1, wc = w & 1;
    const int mt = blockIdx.x & 255;   // M = 32768 -> 256 m-tiles
    const int nt = blockIdx.x >> 8;

    const bf16* Ag = A + (size_t)(mt * 128 + w * 32 + (lane >> 3)) * K + (lane & 7) * 8;
    const bf16* Bg = B + (size_t)(nt * 128 + w * 32 + (lane >> 3)) * K + (lane & 7) * 8;
    bf16* lA = &lsA[(w * 32) * 64];
    bf16* lB = &lsB[(w * 32) * 64];

    f32x4 acc[4][4] = {};

    for (int k0 = 0; k0 < K; k0 += 64) {
        __syncthreads();
        #pragma unroll
        for (int i = 0; i < 4; ++i) {
            GLDS(Ag + (size_t)(i * 8) * K + k0, lA + (i * 8) * 64);
            GLDS(Bg + (size_t)(i * 8) * K + k0, lB + (i * 8) * 64);
        }
        __syncthreads();
        #pragma unroll
        for (int kk = 0; kk < 64; kk += 32) {
            short8 af[4], bq[4];
            #pragma unroll
            for (int i = 0; i < 4; ++i)
                af[i] = *(const short8*)&lsA[(wr * 64 + i * 16 + (lane & 15)) * 64 + kk + (lane >> 4) * 8];
            #pragma unroll
            for (int j = 0; j < 4; ++j)
                bq[j] = *(const short8*)&lsB[(wc * 64 + j * 16 + (lane & 15)) * 64 + kk + (lane >> 4) * 8];
            #pragma unroll
            for (int i = 0; i < 4; ++i)
                #pragma unroll
                for (int j = 0; j < 4; ++j)
                    acc[i][j] = __builtin_amdgcn_mfma_f32_16x16x32_bf16(af[i], bq[j], acc[i][j], 0, 0, 0);
        }
    }

    const int mbase = mt * 128 + wr * 64;
    const int nbase = nt * 128 + wc * 64;
    #pragma unroll
    for (int i = 0; i < 4; ++i) {
        #pragma unroll
        for (int j = 0; j < 4; ++j) {
            const int n = nbase + j * 16 + (lane & 15);
            #pragma unroll
            for (int r = 0; r < 4; ++r) {
                const int m = mbase + i * 16 + (lane >> 4) * 4 + r;
                float v = acc[i][j][r];
                if constexpr (EPI == 1) {
                    v += bias[n];
                    float vo = __shfl_xor(v, 1);
                    // even n: mag col -> Re = min(exp(mag),100)*cos(p)
                    // odd  n: phase col -> Im = min(exp(mag),100)*sin(p)
                    float res = (n & 1) ? fminf(__expf(vo), 100.0f) * __sinf(v)
                                        : fminf(__expf(v), 100.0f) * __cosf(vo);
                    if (n < kNC)
                        O[(size_t)m * LDO + n] = __float2bfloat16(res);
                    else if (n < kKS)
                        O[(size_t)m * LDO + n] = __float2bfloat16(0.0f);
                } else {
                    O[(size_t)m * LDO + n] = __float2bfloat16(v);
                }
            }
        }
    }
}

// ------------------------------------------------------------- overlap-add gather
// out[b, o]: s = o + 384; sum frames[b, t, s - 256 t] for valid t, / (env + eps)
__global__ void ola_k(const bf16* __restrict__ frames, const float* __restrict__ w2g,
                      float* __restrict__ out) {
    __shared__ float w2[1024];
    for (int i = threadIdx.x; i < 1024; i += 256) w2[i] = w2g[i];
    __syncthreads();
    int o  = blockIdx.x * 256 + threadIdx.x;
    int b  = o >> 19;            // 524288 outputs per batch
    int oo = o & 524287;
    int s  = oo + 384;
    int tmax = s >> 8;
    float sum = 0.0f, env = 0.0f;
    #pragma unroll
    for (int jj = 0; jj < 4; ++jj) {
        int t = tmax - jj;
        if (t >= 0 && t < 2048) {
            int n = s - (t << 8);    // always in [0,1024)
            sum += __bfloat162float(frames[(((size_t)b * 2048 + t) << 10) + n]);
            env += w2[n];
        }
    }
    out[o] = sum / (env + 1e-11f);
}

// ---------------------------------------------------------------------- launcher
extern "C" void kernel_launch(void* const* d_in, const int* in_sizes, int n_in,
                              void* d_out, int out_size, void* d_ws, size_t ws_size,
                              hipStream_t stream)
{
    const float* x = (const float*)d_in[0];   // (16, 2048, 512)
    const float* W = (const float*)d_in[1];   // (512, 1026)
    const float* b = (const float*)d_in[2];   // (1026,)
    float* out = (float*)d_out;               // (16, 524288) f32

    char* ws = (char*)d_ws;
    size_t off = 0;
    auto alloc = [&](size_t bytes) { char* p = ws + off; off += (bytes + 255) & ~255ull; return p; };

    bf16*  Mw  = (bf16*) alloc(1024ull * 1088 * 2);    // windowed DFT matrix
    float* w2  = (float*)alloc(1024 * 4);              // window^2 table
    float* br  = (float*)alloc(1152 * 4);              // rearranged bias
    bf16*  Sri = (bf16*) alloc(32768ull * 1088 * 2);   // interleaved (Re,Im)
    char*  regC = alloc(67108864ull);                  // aliased region
    bf16*  xb     = (bf16*)regC;                       // x in bf16 (GEMM1 only)
    bf16*  Wr     = (bf16*)(regC + 33554432ull);       // rearranged W (GEMM1 only)
    bf16*  frames = (bf16*)regC;                       // GEMM2 out (aliases xb+Wr)

    cvt_x_k <<<dim3(8192),     dim3(256), 0, stream>>>(x, xb);   // 16.7M / 8 / 256
    prep_w_k<<<dim3(1152),     dim3(256), 0, stream>>>(W, b, Wr, br);
    prep_m_k<<<dim3(1024),     dim3(256), 0, stream>>>(Mw, w2);
    // GEMM1: (32768 x 512) @ Wr^T -> S_ri (32768 x 1088), fused exp/cos/sin
    gemm_k<512, 1088, 1> <<<dim3(256 * 9), dim3(256), 0, stream>>>(xb, Wr, br, Sri);
    // GEMM2: (32768 x 1088) @ Mw^T -> windowed frames (32768 x 1024)
    gemm_k<1088, 1024, 0><<<dim3(256 * 8), dim3(256), 0, stream>>>(Sri, Mw, nullptr, frames);
    // OLA + envelope normalize + trim
    ola_k   <<<dim3(32768),    dim3(256), 0, stream>>>(frames, w2, out);
    (void)in_sizes; (void)n_in; (void)out_size; (void)ws_size;
}

// Round 3
// 241.302 us; speedup vs baseline: 1.1083x; 1.1083x over previous
//
#include <hip/hip_runtime.h>
#include <hip/hip_bf16.h>
#include <cstdint>
#include <cstddef>

typedef __hip_bfloat16 bf16;
using short8 = __attribute__((ext_vector_type(8))) short;
using f32x4  = __attribute__((ext_vector_type(4))) float;

static constexpr int   kNC    = 1026;   // n_fft + 2
static constexpr int   kKS    = 1088;   // padded S_ri cols (17*64)
static constexpr float kTwoPi = 6.283185307179586f;

#define GLDS(g, l) __builtin_amdgcn_global_load_lds(                       \
    (const __attribute__((address_space(1))) uint32_t*)(g),                \
    (__attribute__((address_space(3))) uint32_t*)(l), 16, 0, 0)

// ---------------------------------------------------------------- prep: x -> bf16
__global__ void cvt_x_k(const float* __restrict__ x, bf16* __restrict__ xb) {
    size_t i = ((size_t)blockIdx.x * 256 + threadIdx.x) * 8;
    float4 a = *(const float4*)(x + i);
    float4 c = *(const float4*)(x + i + 4);
    union { bf16 h[8]; uint4 u; } o;
    o.h[0] = __float2bfloat16(a.x); o.h[1] = __float2bfloat16(a.y);
    o.h[2] = __float2bfloat16(a.z); o.h[3] = __float2bfloat16(a.w);
    o.h[4] = __float2bfloat16(c.x); o.h[5] = __float2bfloat16(c.y);
    o.h[6] = __float2bfloat16(c.z); o.h[7] = __float2bfloat16(c.w);
    *(uint4*)(xb + i) = o.u;
}

// ------------------------------------------- prep: W -> Wr [1280][512] interleaved
__global__ void prep_w_k(const float* __restrict__ W, const float* __restrict__ b,
                         bf16* __restrict__ Wr, float* __restrict__ br) {
    int j = blockIdx.x;
    int col = -1;
    if (j < 1024)      col = (j & 1) ? 513 + (j >> 1) : (j >> 1);
    else if (j == 1024) col = 512;
    else if (j == 1025) col = 1025;
    for (int k = threadIdx.x; k < 512; k += 256) {
        float v = (col >= 0) ? W[(size_t)k * 1026 + col] : 0.0f;
        Wr[(size_t)j * 512 + k] = __float2bfloat16(v);
    }
    if (threadIdx.x == 0) br[j] = (col >= 0) ? b[col] : 0.0f;
}

// --------------------- prep: windowed irfft matrix Mw [1024 rows n][1088 cols kk]
__global__ void prep_m_k(bf16* __restrict__ Mw, float* __restrict__ w2) {
    int nrow = blockIdx.x;
    float wn = 0.5f - 0.5f * cosf(kTwoPi * (float)nrow / 1023.0f);  // numpy hanning
    for (int kk = threadIdx.x; kk < 1088; kk += 256) {
        float v = 0.0f;
        if (kk < 1026) {
            int k = kk >> 1;
            int mm = (k * nrow) & 1023;
            float ang = kTwoPi * (float)mm * (1.0f / 1024.0f);
            float alpha = (k == 0 || k == 512) ? 1.0f : 2.0f;
            float tw = (kk & 1) ? -sinf(ang) : cosf(ang);
            v = alpha * (1.0f / 1024.0f) * wn * tw;
        }
        Mw[(size_t)nrow * 1088 + kk] = __float2bfloat16(v);
    }
    if (threadIdx.x == 0) w2[nrow] = wn * wn;
}

// ------------------------------------------------- 256x256 deep-pipelined bf16 GEMM
// C = A(MxK) * B^T (B stored [n][k]); BK=64; 8 waves 2x4, per-wave 128x64 output.
// LDS: 2 slabs x (A 256x64 + B 256x64) bf16 = 128 KiB, XOR-swizzled 16B slots.
// Counted vmcnt(8): tile t+2's loads stay in flight across the slab barrier.
template<int K, int LDO, int EPI, int MT>
__global__ __launch_bounds__(512, 2)
void gemm256_k(const bf16* __restrict__ A, const bf16* __restrict__ B,
               const float* __restrict__ bias, bf16* __restrict__ O)
{
    extern __shared__ bf16 lds[];            // [2][32768] : A 16384 | B 16384 per slab
    constexpr int NT = K / 64;

    const int tid  = threadIdx.x;
    const int w    = tid >> 6;
    const int lane = tid & 63;
    const int wr = w >> 2, wc = w & 3;       // wave grid 2 (M) x 4 (N)

    const int nwg  = gridDim.x;
    const int orig = blockIdx.x;
    const int bid  = (orig & 7) * (nwg >> 3) + (orig >> 3);   // XCD-contiguous chunks
    const int mt = bid % MT;
    const int nt = bid / MT;
    const int row0 = mt * 256;
    const int col0 = nt * 256;

    // staging geometry: chunk c = w*4+l covers stored rows 8c..8c+7 (1 KiB linear)
    const int srow  = lane >> 3;             // row within chunk (== row & 7)
    const int sslot = (lane & 7) ^ srow;     // pre-swizzled global 16B-slot

    const bf16* gA0 = A + (size_t)(row0 + srow) * K + sslot * 8;
    const bf16* gB0 = B + (size_t)(col0 + srow) * K + sslot * 8;

    auto stage = [&](int t, int s) {
        bf16* lA = lds + s * 32768;
        bf16* lB = lA + 16384;
        #pragma unroll
        for (int l = 0; l < 4; ++l) {
            const int c = w * 4 + l;
            GLDS(gA0 + (size_t)(8 * c) * K + t * 64, lA + c * 512 + lane * 8);
            GLDS(gB0 + (size_t)(8 * c) * K + t * 64, lB + c * 512 + lane * 8);
        }
    };

    f32x4 acc[8][4] = {};

    stage(0, 0);
    if (NT > 1) stage(1, 1);
    asm volatile("s_waitcnt vmcnt(8)" ::: "memory");
    __builtin_amdgcn_sched_barrier(0);
    __builtin_amdgcn_s_barrier();
    asm volatile("" ::: "memory");

    for (int t = 0; t < NT; ++t) {
        bf16* lA = lds + (t & 1) * 32768;
        bf16* lB = lA + 16384;

        short8 bq[4][2];
        #pragma unroll
        for (int fn = 0; fn < 4; ++fn)
            #pragma unroll
            for (int ks = 0; ks < 2; ++ks) {
                const int row = wc * 64 + fn * 16 + (lane & 15);
                const int sl  = (ks * 4 + (lane >> 4)) ^ (row & 7);
                bq[fn][ks] = *(const short8*)(lB + row * 64 + sl * 8);
            }

        #pragma unroll
        for (int q = 0; q < 4; ++q) {
            short8 af[2][2];
            #pragma unroll
            for (int i = 0; i < 2; ++i)
                #pragma unroll
                for (int ks = 0; ks < 2; ++ks) {
                    const int row = wr * 128 + (q * 2 + i) * 16 + (lane & 15);
                    const int sl  = (ks * 4 + (lane >> 4)) ^ (row & 7);
                    af[i][ks] = *(const short8*)(lA + row * 64 + sl * 8);
                }
            if (q == 3) {
                // this wave's LDS reads of slab (t&1) complete:
                asm volatile("s_waitcnt lgkmcnt(0)" ::: "memory");
                __builtin_amdgcn_sched_barrier(0);
                __builtin_amdgcn_s_barrier();        // all waves done reading slab
                asm volatile("" ::: "memory");
                if (t + 2 < NT) {
                    stage(t + 2, t & 1);             // recycle slab; loads stay in flight
                    asm volatile("s_waitcnt vmcnt(8)" ::: "memory");   // tile t+1 resident
                } else if (t + 1 < NT) {
                    asm volatile("s_waitcnt vmcnt(0)" ::: "memory");   // epilogue drain
                }
                __builtin_amdgcn_sched_barrier(0);
                __builtin_amdgcn_s_barrier();        // next slab visible to all waves
                asm volatile("" ::: "memory");
            }
            __builtin_amdgcn_s_setprio(1);
            #pragma unroll
            for (int i = 0; i < 2; ++i)
                #pragma unroll
                for (int fn = 0; fn < 4; ++fn)
                    #pragma unroll
                    for (int ks = 0; ks < 2; ++ks)
                        acc[q * 2 + i][fn] = __builtin_amdgcn_mfma_f32_16x16x32_bf16(
                            af[i][ks], bq[fn][ks], acc[q * 2 + i][fn], 0, 0, 0);
            __builtin_amdgcn_s_setprio(0);
        }
    }

    const int mb = row0 + wr * 128;
    const int nb = col0 + wc * 64;
    #pragma unroll
    for (int i = 0; i < 8; ++i) {
        #pragma unroll
        for (int fn = 0; fn < 4; ++fn) {
            const int n = nb + fn * 16 + (lane & 15);
            #pragma unroll
            for (int r = 0; r < 4; ++r) {
                const int m = mb + i * 16 + (lane >> 4) * 4 + r;
                float v = acc[i][fn][r];
                if constexpr (EPI == 1) {
                    v += bias[n];
                    float vo = __shfl_xor(v, 1);
                    float res = (n & 1) ? fminf(__expf(vo), 100.0f) * __sinf(v)
                                        : fminf(__expf(v), 100.0f) * __cosf(vo);
                    if (n < kNC)
                        O[(size_t)m * LDO + n] = __float2bfloat16(res);
                    else if (n < kKS)
                        O[(size_t)m * LDO + n] = __float2bfloat16(0.0f);
                } else {
                    O[(size_t)m * LDO + n] = __float2bfloat16(v);
                }
            }
        }
    }
}

// ------------------------------------------------------------- overlap-add gather
__global__ void ola_k(const bf16* __restrict__ frames, const float* __restrict__ w2g,
                      float* __restrict__ out) {
    __shared__ float w2[1024];
    for (int i = threadIdx.x; i < 1024; i += 256) w2[i] = w2g[i];
    __syncthreads();
    int o  = blockIdx.x * 256 + threadIdx.x;
    int b  = o >> 19;
    int oo = o & 524287;
    int s  = oo + 384;
    int tmax = s >> 8;
    float sum = 0.0f, env = 0.0f;
    #pragma unroll
    for (int jj = 0; jj < 4; ++jj) {
        int t = tmax - jj;
        if (t >= 0 && t < 2048) {
            int n = s - (t << 8);
            sum += __bfloat162float(frames[(((size_t)b * 2048 + t) << 10) + n]);
            env += w2[n];
        }
    }
    out[o] = sum / (env + 1e-11f);
}

// ---------------------------------------------------------------------- launcher
extern "C" void kernel_launch(void* const* d_in, const int* in_sizes, int n_in,
                              void* d_out, int out_size, void* d_ws, size_t ws_size,
                              hipStream_t stream)
{
    const float* x = (const float*)d_in[0];
    const float* W = (const float*)d_in[1];
    const float* b = (const float*)d_in[2];
    float* out = (float*)d_out;

    char* ws = (char*)d_ws;
    size_t off = 0;
    auto alloc = [&](size_t bytes) { char* p = ws + off; off += (bytes + 255) & ~255ull; return p; };

    bf16*  Mw  = (bf16*) alloc(1024ull * 1088 * 2);
    float* w2  = (float*)alloc(1024 * 4);
    float* br  = (float*)alloc(1280 * 4);
    bf16*  Sri = (bf16*) alloc(32768ull * 1088 * 2);
    char*  regC = alloc(67108864ull);
    bf16*  xb     = (bf16*)regC;
    bf16*  Wr     = (bf16*)(regC + 33554432ull);       // [1280][512]
    bf16*  frames = (bf16*)regC;

    hipFuncSetAttribute(reinterpret_cast<const void*>(gemm256_k<512, 1088, 1, 128>),
                        hipFuncAttributeMaxDynamicSharedMemorySize, 131072);
    hipFuncSetAttribute(reinterpret_cast<const void*>(gemm256_k<1088, 1024, 0, 128>),
                        hipFuncAttributeMaxDynamicSharedMemorySize, 131072);

    cvt_x_k <<<dim3(8192), dim3(256), 0, stream>>>(x, xb);
    prep_w_k<<<dim3(1280), dim3(256), 0, stream>>>(W, b, Wr, br);
    prep_m_k<<<dim3(1024), dim3(256), 0, stream>>>(Mw, w2);
    // GEMM1: (32768 x 1280) = xb @ Wr^T, fused exp/cos/sin -> Sri (LDO 1088)
    gemm256_k<512, 1088, 1, 128><<<dim3(640), dim3(512), 131072, stream>>>(xb, Wr, br, Sri);
    // GEMM2: (32768 x 1024) = Sri @ Mw^T -> windowed frames
    gemm256_k<1088, 1024, 0, 128><<<dim3(512), dim3(512), 131072, stream>>>(Sri, Mw, nullptr, frames);
    ola_k   <<<dim3(32768), dim3(256), 0, stream>>>(frames, w2, out);
    (void)in_sizes; (void)n_in; (void)out_size; (void)ws_size;
}